// Round 3
// baseline (839.821 us; speedup 1.0000x reference)
//
#include <hip/hip_runtime.h>
#include <math.h>

#define DM 3136
#define DH 512

// ---------------- conv3x3 (SAME, NHWC semantics) + channel-RMSNorm ----------------
__global__ __launch_bounds__(256) void conv_rms(
    const float* __restrict__ x,
    const float* __restrict__ wk, const float* __restrict__ bk,
    const float* __restrict__ wv, const float* __restrict__ bv,
    const float* __restrict__ sk, const float* __restrict__ sv,
    float* __restrict__ nk, float* __restrict__ nv) {
  __shared__ float swk[144], swv[144], sb[16];
  int tid = threadIdx.x;
  if (tid < 144) { swk[tid] = wk[tid]; swv[tid] = wv[tid]; }
  if (tid < 4) {
    sb[tid] = bk[tid]; sb[4 + tid] = bv[tid];
    sb[8 + tid] = sk[tid]; sb[12 + tid] = sv[tid];
  }
  __syncthreads();
  int idx = blockIdx.x * 256 + tid;          // t*784 + hw
  int t = idx / 784, hw = idx - t * 784;
  int h = hw / 28, w = hw - h * 28;
  float ak[4], av[4];
  #pragma unroll
  for (int c = 0; c < 4; ++c) { ak[c] = sb[c]; av[c] = sb[4 + c]; }
  const float* xt = x + (size_t)t * DM;
  for (int kh = 0; kh < 3; ++kh) {
    int ih = h + kh - 1;
    if (ih < 0 || ih >= 28) continue;
    for (int kw = 0; kw < 3; ++kw) {
      int iw = w + kw - 1;
      if (iw < 0 || iw >= 28) continue;
      int base = (kh * 3 + kw) * 16;
      #pragma unroll
      for (int ci = 0; ci < 4; ++ci) {
        float xv = xt[ci * 784 + ih * 28 + iw];
        #pragma unroll
        for (int co = 0; co < 4; ++co) {
          ak[co] += xv * swk[base + ci * 4 + co];
          av[co] += xv * swv[base + ci * 4 + co];
        }
      }
    }
  }
  float mk = (ak[0]*ak[0] + ak[1]*ak[1] + ak[2]*ak[2] + ak[3]*ak[3]) * 0.25f + 1e-6f;
  float mv = (av[0]*av[0] + av[1]*av[1] + av[2]*av[2] + av[3]*av[3]) * 0.25f + 1e-6f;
  float ik = 1.f / sqrtf(mk), iv = 1.f / sqrtf(mv);
  float4 ok = { ak[0]*ik*sb[8],  ak[1]*ik*sb[9],  ak[2]*ik*sb[10], ak[3]*ik*sb[11] };
  float4 ov = { av[0]*iv*sb[12], av[1]*iv*sb[13], av[2]*iv*sb[14], av[3]*iv*sb[15] };
  *(float4*)&nk[(size_t)idx * 4] = ok;
  *(float4*)&nv[(size_t)idx * 4] = ov;
}

// ---------------- mm64_nn: A[64,K]@B -> split-K slices (proven) ----------------
__global__ __launch_bounds__(256) void mm64_nn(
    const float* __restrict__ A, int lda,
    const float* __restrict__ B, int ldb,
    float* __restrict__ Cp, int ldc) {
  __shared__ float As[64][64];
  __shared__ float Bs[64][64];
  int tid = threadIdx.x;
  int n0 = blockIdx.x * 64;
  int k0 = blockIdx.y * 64;
  {
    int m  = tid >> 2;
    int kb = (tid & 3) * 16;
    const float* Ap = A + (size_t)m * lda + k0 + kb;
    #pragma unroll
    for (int q = 0; q < 4; ++q) {
      float4 v = *(const float4*)(Ap + q * 4);
      As[kb + q*4 + 0][m] = v.x;
      As[kb + q*4 + 1][m] = v.y;
      As[kb + q*4 + 2][m] = v.z;
      As[kb + q*4 + 3][m] = v.w;
    }
    int kr = tid >> 4;
    int nn = (tid & 15) * 4;
    #pragma unroll
    for (int q = 0; q < 4; ++q) {
      float4 v = *(const float4*)(B + (size_t)(k0 + kr + q*16) * ldb + n0 + nn);
      *(float4*)&Bs[kr + q*16][nn] = v;
    }
  }
  __syncthreads();
  int tx = tid & 15, ty = tid >> 4;
  float acc[4][4] = {{0.f}};
  #pragma unroll 16
  for (int kk = 0; kk < 64; ++kk) {
    float4 a = *(const float4*)&As[kk][ty * 4];
    float4 b = *(const float4*)&Bs[kk][tx * 4];
    acc[0][0] += a.x*b.x; acc[0][1] += a.x*b.y; acc[0][2] += a.x*b.z; acc[0][3] += a.x*b.w;
    acc[1][0] += a.y*b.x; acc[1][1] += a.y*b.y; acc[1][2] += a.y*b.z; acc[1][3] += a.y*b.w;
    acc[2][0] += a.z*b.x; acc[2][1] += a.z*b.y; acc[2][2] += a.z*b.z; acc[2][3] += a.z*b.w;
    acc[3][0] += a.w*b.x; acc[3][1] += a.w*b.y; acc[3][2] += a.w*b.z; acc[3][3] += a.w*b.w;
  }
  float* Cb = Cp + (size_t)blockIdx.y * 64 * ldc + n0 + tx * 4;
  #pragma unroll
  for (int r = 0; r < 4; ++r) {
    float4 v = { acc[r][0], acc[r][1], acc[r][2], acc[r][3] };
    *(float4*)&Cb[(size_t)(ty * 4 + r) * ldc] = v;
  }
}

// ---------------- mm64_nt: A[64,K]@B^T, B [N,K] row-major (proven) ----------------
__global__ __launch_bounds__(256) void mm64_nt(
    const float* __restrict__ A, int lda,
    const float* __restrict__ B, int ldb,
    float* __restrict__ Cp, int ldc) {
  __shared__ float As[64][64];
  __shared__ float Bs[64][64];
  int tid = threadIdx.x;
  int n0 = blockIdx.x * 64;
  int k0 = blockIdx.y * 64;
  {
    int m  = tid >> 2;
    int kb = (tid & 3) * 16;
    const float* Ap = A + (size_t)m * lda + k0 + kb;
    const float* Bp = B + (size_t)(n0 + m) * ldb + k0 + kb;
    #pragma unroll
    for (int q = 0; q < 4; ++q) {
      float4 va = *(const float4*)(Ap + q * 4);
      As[kb + q*4 + 0][m] = va.x;
      As[kb + q*4 + 1][m] = va.y;
      As[kb + q*4 + 2][m] = va.z;
      As[kb + q*4 + 3][m] = va.w;
      float4 vb = *(const float4*)(Bp + q * 4);
      Bs[kb + q*4 + 0][m] = vb.x;
      Bs[kb + q*4 + 1][m] = vb.y;
      Bs[kb + q*4 + 2][m] = vb.z;
      Bs[kb + q*4 + 3][m] = vb.w;
    }
  }
  __syncthreads();
  int tx = tid & 15, ty = tid >> 4;
  float acc[4][4] = {{0.f}};
  #pragma unroll 16
  for (int kk = 0; kk < 64; ++kk) {
    float4 a = *(const float4*)&As[kk][ty * 4];
    float4 b = *(const float4*)&Bs[kk][tx * 4];
    acc[0][0] += a.x*b.x; acc[0][1] += a.x*b.y; acc[0][2] += a.x*b.z; acc[0][3] += a.x*b.w;
    acc[1][0] += a.y*b.x; acc[1][1] += a.y*b.y; acc[1][2] += a.y*b.z; acc[1][3] += a.y*b.w;
    acc[2][0] += a.z*b.x; acc[2][1] += a.z*b.y; acc[2][2] += a.z*b.z; acc[2][3] += a.z*b.w;
    acc[3][0] += a.w*b.x; acc[3][1] += a.w*b.y; acc[3][2] += a.w*b.z; acc[3][3] += a.w*b.w;
  }
  float* Cb = Cp + (size_t)blockIdx.y * 64 * ldc + n0 + tx * 4;
  #pragma unroll
  for (int r = 0; r < 4; ++r) {
    float4 v = { acc[r][0], acc[r][1], acc[r][2], acc[r][3] };
    *(float4*)&Cb[(size_t)(ty * 4 + r) * ldc] = v;
  }
}

// ---------------- upd64 device body: Cnew = Cold - A^T B (in-place safe) ----------------
__device__ __forceinline__ void upd64_dev(
    const float* __restrict__ A, int P,
    const float* __restrict__ B, int Q,
    const float* __restrict__ Cold, float* __restrict__ Cnew,
    int bx, int by, float* smem) {
  float* As = smem;          // [64][64] i-major: As[i*64+p]
  float* Bs = smem + 4096;
  int tid = threadIdx.x;
  int q0 = bx * 64;
  int p0 = by * 64;
  {
    int i = tid >> 4;
    int c = (tid & 15) * 4;
    #pragma unroll
    for (int q = 0; q < 4; ++q) {
      *(float4*)&As[(i + q*16)*64 + c] = *(const float4*)(A + (size_t)(i + q*16) * P + p0 + c);
      *(float4*)&Bs[(i + q*16)*64 + c] = *(const float4*)(B + (size_t)(i + q*16) * Q + q0 + c);
    }
  }
  __syncthreads();
  int tx = tid & 15, ty = tid >> 4;
  float acc[4][4] = {{0.f}};
  #pragma unroll 16
  for (int i = 0; i < 64; ++i) {
    float4 a = *(const float4*)&As[i*64 + ty * 4];
    float4 b = *(const float4*)&Bs[i*64 + tx * 4];
    acc[0][0] += a.x*b.x; acc[0][1] += a.x*b.y; acc[0][2] += a.x*b.z; acc[0][3] += a.x*b.w;
    acc[1][0] += a.y*b.x; acc[1][1] += a.y*b.y; acc[1][2] += a.y*b.z; acc[1][3] += a.y*b.w;
    acc[2][0] += a.z*b.x; acc[2][1] += a.z*b.y; acc[2][2] += a.z*b.z; acc[2][3] += a.z*b.w;
    acc[3][0] += a.w*b.x; acc[3][1] += a.w*b.y; acc[3][2] += a.w*b.z; acc[3][3] += a.w*b.w;
  }
  #pragma unroll
  for (int r = 0; r < 4; ++r) {
    size_t off = (size_t)(p0 + ty*4 + r) * Q + q0 + tx*4;
    float4 co = *(const float4*)&Cold[off];
    float4 v = { co.x - acc[r][0], co.y - acc[r][1], co.z - acc[r][2], co.w - acc[r][3] };
    *(float4*)&Cnew[off] = v;
  }
}

// ---------------- gelu ----------------
__device__ __forceinline__ void gelu_both(float xx, float& g, float& gp) {
  const float c = 0.7978845608028654f;
  const float a = 0.044715f;
  float x2 = xx * xx;
  float u = c * (xx + a * xx * x2);
  float t = tanhf(u);
  g  = 0.5f * xx * (1.f + t);
  gp = 0.5f * (1.f + t) + 0.5f * xx * (1.f - t * t) * c * (1.f + 3.f * a * x2);
}
__device__ __forceinline__ float gelu_only(float xx) {
  const float c = 0.7978845608028654f;
  const float a = 0.044715f;
  float u = c * (xx + a * xx * xx * xx);
  return 0.5f * xx * (1.f + tanhf(u));
}

// ---------------- P2: reduce 49 H-slices + bias -> H (pre-bias), G, Gp ----------------
__global__ __launch_bounds__(256) void red_gelu(
    const float* __restrict__ Hp, const float* __restrict__ b1,
    float* __restrict__ H, float* __restrict__ G, float* __restrict__ Gp) {
  int j = blockIdx.x * 256 + threadIdx.x;    // < 32768
  float s = 0.f;
  #pragma unroll
  for (int t = 0; t < 49; ++t) s += Hp[(size_t)t * 32768 + j];
  H[j] = s;                                  // pre-bias, for the H2 trick
  float x = s + b1[j & 511];
  float g, gp;
  gelu_both(x, g, gp);
  G[j] = g; Gp[j] = gp;
}

// ---------------- P3/P7: fused full-K GEMM  C = A[64,512] @ B[512,3136] tile 64x16 ----------------
// mode 0: Dw = wc2*(C + bias - V); b2out = bias - colsum(Dw)
// mode 1: out[(t0+m)*DM + col] = C + bias
__global__ __launch_bounds__(256) void mmPY(
    const float* __restrict__ A, const float* __restrict__ B,
    const float* __restrict__ V, const float* __restrict__ bias_in,
    float* __restrict__ b2out, float* __restrict__ Dw,
    float* __restrict__ out, int t0, float wc2, int mode) {
  __shared__ float As[64][64];
  __shared__ float Bs[64][16];
  int tid = threadIdx.x;
  int n0 = blockIdx.x * 16;
  int tx = tid & 15, ty = tid >> 4;
  float acc[4] = {0.f, 0.f, 0.f, 0.f};
  for (int k0 = 0; k0 < 512; k0 += 64) {
    {
      int m  = tid >> 2;
      int kb = (tid & 3) * 16;
      const float* Ap = A + (size_t)m * 512 + k0 + kb;
      #pragma unroll
      for (int q = 0; q < 4; ++q) {
        float4 v = *(const float4*)(Ap + q * 4);
        As[kb + q*4 + 0][m] = v.x;
        As[kb + q*4 + 1][m] = v.y;
        As[kb + q*4 + 2][m] = v.z;
        As[kb + q*4 + 3][m] = v.w;
      }
      int kr = tid >> 2;
      int nc = (tid & 3) * 4;
      *(float4*)&Bs[kr][nc] = *(const float4*)(B + (size_t)(k0 + kr) * DM + n0 + nc);
    }
    __syncthreads();
    #pragma unroll 16
    for (int kk = 0; kk < 64; ++kk) {
      float4 a = *(const float4*)&As[kk][ty * 4];
      float b = Bs[kk][tx];
      acc[0] += a.x * b; acc[1] += a.y * b; acc[2] += a.z * b; acc[3] += a.w * b;
    }
    __syncthreads();
  }
  int col = n0 + tx;
  if (mode == 0) {
    float bb = bias_in[col];
    float cs = 0.f;
    #pragma unroll
    for (int r = 0; r < 4; ++r) {
      int m = ty * 4 + r;
      float d = wc2 * (acc[r] + bb - V[(size_t)m * DM + col]);
      Dw[(size_t)m * DM + col] = d;
      cs += d;
    }
    float* part = &As[0][0];     // safe: last loop iter ended with __syncthreads
    part[ty * 16 + tx] = cs;
    __syncthreads();
    if (tid < 16) {
      float s = 0.f;
      #pragma unroll
      for (int j = 0; j < 16; ++j) s += part[j * 16 + tid];
      b2out[n0 + tid] = bias_in[n0 + tid] - s;
    }
  } else {
    float bb = bias_in[col];
    #pragma unroll
    for (int r = 0; r < 4; ++r) {
      int m = ty * 4 + r;
      out[(size_t)(t0 + m) * DM + col] = acc[r] + bb;
    }
  }
}

// ---------------- KK precompute: KKs[c][s] = K_c[:,s*448:+448] · K_c^T partial ----------------
__global__ __launch_bounds__(256) void kk_pre(
    const float* __restrict__ nk, float* __restrict__ KKs) {
  __shared__ float As[64][64];
  int tid = threadIdx.x;
  int c = blockIdx.x;        // chunk
  int s = blockIdx.y;        // k-split (7 x 448)
  const float* K = nk + (size_t)c * 64 * DM;
  int tx = tid & 15, ty = tid >> 4;
  float acc[4][4] = {{0.f}};
  for (int ks = 0; ks < 7; ++ks) {
    int kb0 = s * 448 + ks * 64;
    {
      int m  = tid >> 2;
      int kb = (tid & 3) * 16;
      const float* Ap = K + (size_t)m * DM + kb0 + kb;
      #pragma unroll
      for (int q = 0; q < 4; ++q) {
        float4 v = *(const float4*)(Ap + q * 4);
        As[kb + q*4 + 0][m] = v.x;
        As[kb + q*4 + 1][m] = v.y;
        As[kb + q*4 + 2][m] = v.z;
        As[kb + q*4 + 3][m] = v.w;
      }
    }
    __syncthreads();
    #pragma unroll 16
    for (int kk = 0; kk < 64; ++kk) {
      float4 a = *(const float4*)&As[kk][ty * 4];
      float4 b = *(const float4*)&As[kk][tx * 4];
      acc[0][0] += a.x*b.x; acc[0][1] += a.x*b.y; acc[0][2] += a.x*b.z; acc[0][3] += a.x*b.w;
      acc[1][0] += a.y*b.x; acc[1][1] += a.y*b.y; acc[1][2] += a.y*b.z; acc[1][3] += a.y*b.w;
      acc[2][0] += a.z*b.x; acc[2][1] += a.z*b.y; acc[2][2] += a.z*b.z; acc[2][3] += a.z*b.w;
      acc[3][0] += a.w*b.x; acc[3][1] += a.w*b.y; acc[3][2] += a.w*b.z; acc[3][3] += a.w*b.w;
    }
    __syncthreads();
  }
  float* dst = KKs + (size_t)(c * 7 + s) * 4096;
  #pragma unroll
  for (int r = 0; r < 4; ++r) {
    float4 v = { acc[r][0], acc[r][1], acc[r][2], acc[r][3] };
    *(float4*)&dst[(ty*4 + r) * 64 + tx*4] = v;
  }
}

// ---------------- P5: upd64-W2 (blocks 0..391) || red_E + b1 update (392..519) ----------------
__global__ __launch_bounds__(256) void comb5(
    const float* __restrict__ G, const float* __restrict__ Dw,
    const float* __restrict__ W2old, float* __restrict__ W2new,
    const float* __restrict__ Esl, const float* __restrict__ Gp,
    float* __restrict__ Ew, const float* __restrict__ b1old, float* __restrict__ b1new) {
  __shared__ float smem[8192];
  int li = blockIdx.x;
  int tid = threadIdx.x;
  if (li < 392) {
    // W2new = W2old - G^T Dw ; A=G P=DH, B=Dw Q=DM; grid (49,8)
    upd64_dev(G, DH, Dw, DM, W2old, W2new, li % 49, li / 49, smem);
  } else {
    int li2 = li - 392;                 // 0..127
    int n0 = li2 * 4;
    int row = tid >> 2, c = tid & 3;
    int col = n0 + c;
    float s = 0.f;
    #pragma unroll
    for (int sl = 0; sl < 49; ++sl) s += Esl[(size_t)sl * 32768 + row * 512 + col];
    float ew = s * Gp[row * 512 + col];
    Ew[row * 512 + col] = ew;
    smem[tid] = ew;
    __syncthreads();
    for (int off = 128; off >= 4; off >>= 1) {
      if (tid < off) smem[tid] += smem[tid + off];
      __syncthreads();
    }
    if (tid < 4) b1new[n0 + tid] = b1old[n0 + tid] - smem[tid];
  }
}

// ---------------- P6: upd64-W1 (0..391) || gelu2 via H2 = H - KK@Ew (392..423) ----------------
__global__ __launch_bounds__(256) void comb6(
    const float* __restrict__ K, const float* __restrict__ Ew,
    const float* __restrict__ W1old, float* __restrict__ W1new,
    const float* __restrict__ KKs, int chunk,
    const float* __restrict__ H, const float* __restrict__ b1n,
    float* __restrict__ G2) {
  __shared__ float smem[8192];
  int li = blockIdx.x;
  int tid = threadIdx.x;
  if (li < 392) {
    // W1new = W1old - K^T Ew ; A=K P=DM, B=Ew Q=DH; grid (8,49)
    upd64_dev(K, DM, Ew, DH, W1old, W1new, li % 8, li / 8, smem);
  } else {
    int li2 = li - 392;                 // 0..31
    int n0 = li2 * 16;
    float* KKsum = smem;                // 4096: [m][i]
    float* Ews   = smem + 4096;         // 1024: [i][cc]
    const float* base = KKs + (size_t)chunk * 7 * 4096;
    for (int e = tid; e < 4096; e += 256) {
      float s = 0.f;
      #pragma unroll
      for (int sl = 0; sl < 7; ++sl) s += base[sl * 4096 + e];
      KKsum[e] = s;
    }
    for (int e = tid; e < 1024; e += 256) {
      int i = e >> 4, cc = e & 15;
      Ews[e] = Ew[i * 512 + n0 + cc];
    }
    __syncthreads();
    for (int e = tid; e < 1024; e += 256) {
      int m = e >> 4, cc = e & 15;
      float corr = 0.f;
      #pragma unroll 16
      for (int i = 0; i < 64; ++i) corr += KKsum[m * 64 + i] * Ews[i * 16 + cc];
      float xx = H[m * 512 + n0 + cc] - corr + b1n[n0 + cc];
      G2[m * 512 + n0 + cc] = gelu_only(xx);
    }
  }
}

extern "C" void kernel_launch(void* const* d_in, const int* in_sizes, int n_in,
                              void* d_out, int out_size, void* d_ws, size_t ws_size,
                              hipStream_t stream) {
  const float* x  = (const float*)d_in[0];
  const float* wk = (const float*)d_in[1];
  const float* bk = (const float*)d_in[2];
  const float* wv = (const float*)d_in[3];
  const float* bv = (const float*)d_in[4];
  const float* sk = (const float*)d_in[5];
  const float* sv = (const float*)d_in[6];
  const float* W1 = (const float*)d_in[7];
  const float* b1 = (const float*)d_in[8];
  const float* W2 = (const float*)d_in[9];
  const float* b2 = (const float*)d_in[10];
  float* out = (float*)d_out;
  float* ws  = (float*)d_ws;

  // workspace layout (floats)
  float* nk    = ws;                 // 1605632
  float* nv    = ws + 1605632;       // 1605632
  float* W1ws  = ws + 3211264;       // 1605632 (in-place after chunk 0)
  float* W2ws  = ws + 4816896;       // 1605632
  float* Spart = ws + 6422528;       // 1605632 (49 x [64,512] slices, H then E)
  float* H     = ws + 8028160;       // 32768 (pre-bias)
  float* G     = ws + 8060928;       // 32768 (G, later G2)
  float* Gp    = ws + 8093696;       // 32768
  float* Ew    = ws + 8126464;       // 32768
  float* Dw    = ws + 8159232;       // 200704
  float* KKs   = ws + 8359936;       // 229376 = 8 chunks x 7 slices x 4096
  float* b1ws  = ws + 8589312;       // 512
  float* b2ws  = ws + 8589824;       // 3136

  conv_rms<<<1568, 256, 0, stream>>>(x, wk, bk, wv, bv, sk, sv, nk, nv);
  kk_pre<<<dim3(8, 7), 256, 0, stream>>>(nk, KKs);

  // weights[i] = ETA0 * ALPHA^i * (ALPHA^63 / ALPHA^i) = ETA0 * ALPHA^63 (constant)
  float wc2 = 2.0f * (float)(0.1 * pow(0.9, 63.0));

  for (int ch = 0; ch < 8; ++ch) {
    const float* K = nk + (size_t)ch * 64 * DM;
    const float* V = nv + (size_t)ch * 64 * DM;
    const float* W1c = ch ? W1ws : W1;
    const float* W2c = ch ? W2ws : W2;
    const float* b1c = ch ? b1ws : b1;
    const float* b2c = ch ? b2ws : b2;

    // P1: H slices = K @ W1c   [64,3136]@[3136,512], split-K 49
    mm64_nn<<<dim3(8, 49), 256, 0, stream>>>(K, DM, W1c, DH, Spart, DH);
    // P2: H (pre-bias), G=gelu(H+b1), Gp
    red_gelu<<<128, 256, 0, stream>>>(Spart, b1c, H, G, Gp);
    // P3: Dw = wc2*(G@W2c + b2 - V), b2ws = b2c - colsum(Dw); full-K, 196 blocks
    mmPY<<<196, 256, 0, stream>>>(G, W2c, V, b2c, b2ws, Dw, (float*)nullptr, 0, wc2, 0);
    // P4: E slices = Dw @ W2c^T, split-K 49
    mm64_nt<<<dim3(8, 49), 256, 0, stream>>>(Dw, DM, W2c, DM, Spart, DH);
    // P5: W2ws = W2c - G^T Dw  ||  Ew = redE*Gp, b1ws = b1c - colsum(Ew)
    comb5<<<520, 256, 0, stream>>>(G, Dw, W2c, W2ws, Spart, Gp, Ew, b1c, b1ws);
    // P6: W1ws = W1c - K^T Ew  ||  G2 = gelu(H - KK@Ew + b1ws)
    comb6<<<424, 256, 0, stream>>>(K, Ew, W1c, W1ws, KKs, ch, H, b1ws, G);
    // P7: out rows = G2 @ W2ws + b2ws (raw reshape, contiguous)
    mmPY<<<196, 256, 0, stream>>>(G, W2ws, (const float*)nullptr, b2ws,
                                  (float*)nullptr, (float*)nullptr, out, ch * 64, wc2, 1);
  }
}

// Round 4
// 678.419 us; speedup vs baseline: 1.2379x; 1.2379x over previous
//
#include <hip/hip_runtime.h>
#include <math.h>

#define DM 3136
#define DH 512

// ---------------- conv3x3 (SAME, NHWC semantics) + channel-RMSNorm ----------------
__global__ __launch_bounds__(256) void conv_rms(
    const float* __restrict__ x,
    const float* __restrict__ wk, const float* __restrict__ bk,
    const float* __restrict__ wv, const float* __restrict__ bv,
    const float* __restrict__ sk, const float* __restrict__ sv,
    float* __restrict__ nk, float* __restrict__ nv) {
  __shared__ float swk[144], swv[144], sb[16];
  int tid = threadIdx.x;
  if (tid < 144) { swk[tid] = wk[tid]; swv[tid] = wv[tid]; }
  if (tid < 4) {
    sb[tid] = bk[tid]; sb[4 + tid] = bv[tid];
    sb[8 + tid] = sk[tid]; sb[12 + tid] = sv[tid];
  }
  __syncthreads();
  int idx = blockIdx.x * 256 + tid;
  int t = idx / 784, hw = idx - t * 784;
  int h = hw / 28, w = hw - h * 28;
  float ak[4], av[4];
  #pragma unroll
  for (int c = 0; c < 4; ++c) { ak[c] = sb[c]; av[c] = sb[4 + c]; }
  const float* xt = x + (size_t)t * DM;
  for (int kh = 0; kh < 3; ++kh) {
    int ih = h + kh - 1;
    if (ih < 0 || ih >= 28) continue;
    for (int kw = 0; kw < 3; ++kw) {
      int iw = w + kw - 1;
      if (iw < 0 || iw >= 28) continue;
      int base = (kh * 3 + kw) * 16;
      #pragma unroll
      for (int ci = 0; ci < 4; ++ci) {
        float xv = xt[ci * 784 + ih * 28 + iw];
        #pragma unroll
        for (int co = 0; co < 4; ++co) {
          ak[co] += xv * swk[base + ci * 4 + co];
          av[co] += xv * swv[base + ci * 4 + co];
        }
      }
    }
  }
  float mk = (ak[0]*ak[0] + ak[1]*ak[1] + ak[2]*ak[2] + ak[3]*ak[3]) * 0.25f + 1e-6f;
  float mv = (av[0]*av[0] + av[1]*av[1] + av[2]*av[2] + av[3]*av[3]) * 0.25f + 1e-6f;
  float ik = 1.f / sqrtf(mk), iv = 1.f / sqrtf(mv);
  float4 ok = { ak[0]*ik*sb[8],  ak[1]*ik*sb[9],  ak[2]*ik*sb[10], ak[3]*ik*sb[11] };
  float4 ov = { av[0]*iv*sb[12], av[1]*iv*sb[13], av[2]*iv*sb[14], av[3]*iv*sb[15] };
  *(float4*)&nk[(size_t)idx * 4] = ok;
  *(float4*)&nv[(size_t)idx * 4] = ov;
}

#define MICRO_4x4(As, Bs) \
    acc[0][0] += a.x*b.x; acc[0][1] += a.x*b.y; acc[0][2] += a.x*b.z; acc[0][3] += a.x*b.w; \
    acc[1][0] += a.y*b.x; acc[1][1] += a.y*b.y; acc[1][2] += a.y*b.z; acc[1][3] += a.y*b.w; \
    acc[2][0] += a.z*b.x; acc[2][1] += a.z*b.y; acc[2][2] += a.z*b.z; acc[2][3] += a.z*b.w; \
    acc[3][0] += a.w*b.x; acc[3][1] += a.w*b.y; acc[3][2] += a.w*b.z; acc[3][3] += a.w*b.w;

// ---------------- mm64_nn: A[64,K]@B -> split-K slices (proven R2) ----------------
__global__ __launch_bounds__(256) void mm64_nn(
    const float* __restrict__ A, int lda,
    const float* __restrict__ B, int ldb,
    float* __restrict__ Cp, int ldc) {
  __shared__ float As[64][64];
  __shared__ float Bs[64][64];
  int tid = threadIdx.x;
  int n0 = blockIdx.x * 64;
  int k0 = blockIdx.y * 64;
  {
    int m  = tid >> 2;
    int kb = (tid & 3) * 16;
    const float* Ap = A + (size_t)m * lda + k0 + kb;
    #pragma unroll
    for (int q = 0; q < 4; ++q) {
      float4 v = *(const float4*)(Ap + q * 4);
      As[kb + q*4 + 0][m] = v.x;
      As[kb + q*4 + 1][m] = v.y;
      As[kb + q*4 + 2][m] = v.z;
      As[kb + q*4 + 3][m] = v.w;
    }
    int kr = tid >> 4;
    int nn = (tid & 15) * 4;
    #pragma unroll
    for (int q = 0; q < 4; ++q) {
      float4 v = *(const float4*)(B + (size_t)(k0 + kr + q*16) * ldb + n0 + nn);
      *(float4*)&Bs[kr + q*16][nn] = v;
    }
  }
  __syncthreads();
  int tx = tid & 15, ty = tid >> 4;
  float acc[4][4] = {{0.f}};
  #pragma unroll 16
  for (int kk = 0; kk < 64; ++kk) {
    float4 a = *(const float4*)&As[kk][ty * 4];
    float4 b = *(const float4*)&Bs[kk][tx * 4];
    MICRO_4x4(As, Bs)
  }
  float* Cb = Cp + (size_t)blockIdx.y * 64 * ldc + n0 + tx * 4;
  #pragma unroll
  for (int r = 0; r < 4; ++r) {
    float4 v = { acc[r][0], acc[r][1], acc[r][2], acc[r][3] };
    *(float4*)&Cb[(size_t)(ty * 4 + r) * ldc] = v;
  }
}

// ---------------- mm64_nt: A[64,K]@B^T, B [N,K] row-major (proven R2) ----------------
__global__ __launch_bounds__(256) void mm64_nt(
    const float* __restrict__ A, int lda,
    const float* __restrict__ B, int ldb,
    float* __restrict__ Cp, int ldc) {
  __shared__ float As[64][64];
  __shared__ float Bs[64][64];
  int tid = threadIdx.x;
  int n0 = blockIdx.x * 64;
  int k0 = blockIdx.y * 64;
  {
    int m  = tid >> 2;
    int kb = (tid & 3) * 16;
    const float* Ap = A + (size_t)m * lda + k0 + kb;
    const float* Bp = B + (size_t)(n0 + m) * ldb + k0 + kb;
    #pragma unroll
    for (int q = 0; q < 4; ++q) {
      float4 va = *(const float4*)(Ap + q * 4);
      As[kb + q*4 + 0][m] = va.x;
      As[kb + q*4 + 1][m] = va.y;
      As[kb + q*4 + 2][m] = va.z;
      As[kb + q*4 + 3][m] = va.w;
      float4 vb = *(const float4*)(Bp + q * 4);
      Bs[kb + q*4 + 0][m] = vb.x;
      Bs[kb + q*4 + 1][m] = vb.y;
      Bs[kb + q*4 + 2][m] = vb.z;
      Bs[kb + q*4 + 3][m] = vb.w;
    }
  }
  __syncthreads();
  int tx = tid & 15, ty = tid >> 4;
  float acc[4][4] = {{0.f}};
  #pragma unroll 16
  for (int kk = 0; kk < 64; ++kk) {
    float4 a = *(const float4*)&As[kk][ty * 4];
    float4 b = *(const float4*)&Bs[kk][tx * 4];
    MICRO_4x4(As, Bs)
  }
  float* Cb = Cp + (size_t)blockIdx.y * 64 * ldc + n0 + tx * 4;
  #pragma unroll
  for (int r = 0; r < 4; ++r) {
    float4 v = { acc[r][0], acc[r][1], acc[r][2], acc[r][3] };
    *(float4*)&Cb[(size_t)(ty * 4 + r) * ldc] = v;
  }
}

// ---------------- upd64 device body: Cnew = Cold - A^T B (in-place safe, proven R3) ----------------
__device__ __forceinline__ void upd64_dev(
    const float* __restrict__ A, int P,
    const float* __restrict__ B, int Q,
    const float* __restrict__ Cold, float* __restrict__ Cnew,
    int bx, int by, float* smem) {
  float* As = smem;
  float* Bs = smem + 4096;
  int tid = threadIdx.x;
  int q0 = bx * 64;
  int p0 = by * 64;
  {
    int i = tid >> 4;
    int c = (tid & 15) * 4;
    #pragma unroll
    for (int q = 0; q < 4; ++q) {
      *(float4*)&As[(i + q*16)*64 + c] = *(const float4*)(A + (size_t)(i + q*16) * P + p0 + c);
      *(float4*)&Bs[(i + q*16)*64 + c] = *(const float4*)(B + (size_t)(i + q*16) * Q + q0 + c);
    }
  }
  __syncthreads();
  int tx = tid & 15, ty = tid >> 4;
  float acc[4][4] = {{0.f}};
  #pragma unroll 16
  for (int i = 0; i < 64; ++i) {
    float4 a = *(const float4*)&As[i*64 + ty * 4];
    float4 b = *(const float4*)&Bs[i*64 + tx * 4];
    MICRO_4x4(As, Bs)
  }
  #pragma unroll
  for (int r = 0; r < 4; ++r) {
    size_t off = (size_t)(p0 + ty*4 + r) * Q + q0 + tx*4;
    float4 co = *(const float4*)&Cold[off];
    float4 v = { co.x - acc[r][0], co.y - acc[r][1], co.z - acc[r][2], co.w - acc[r][3] };
    *(float4*)&Cnew[off] = v;
  }
}

// ---------------- gelu ----------------
__device__ __forceinline__ void gelu_both(float xx, float& g, float& gp) {
  const float c = 0.7978845608028654f;
  const float a = 0.044715f;
  float x2 = xx * xx;
  float u = c * (xx + a * xx * x2);
  float t = tanhf(u);
  g  = 0.5f * xx * (1.f + t);
  gp = 0.5f * (1.f + t) + 0.5f * xx * (1.f - t * t) * c * (1.f + 3.f * a * x2);
}
__device__ __forceinline__ float gelu_only(float xx) {
  const float c = 0.7978845608028654f;
  const float a = 0.044715f;
  float u = c * (xx + a * xx * xx * xx);
  return 0.5f * xx * (1.f + tanhf(u));
}

// ---------------- upfront: KK pair slices  KK[c,j] = K_c K_j^T ----------------
// grid (36 pairs, 7 k-splits of 448)
__global__ __launch_bounds__(256) void kk_pre(
    const float* __restrict__ nk, float* __restrict__ KKsl) {
  __shared__ float As[64][64], Bs[64][64];
  int tid = threadIdx.x;
  int p = blockIdx.x, s = blockIdx.y;
  int c = 0;
  while ((c + 1) * (c + 2) / 2 <= p) ++c;
  int j = p - c * (c + 1) / 2;
  const float* Kc = nk + (size_t)c * 64 * DM;
  const float* Kj = nk + (size_t)j * 64 * DM;
  int tx = tid & 15, ty = tid >> 4;
  int m = tid >> 2, kb = (tid & 3) * 16;
  float acc[4][4] = {{0.f}};
  for (int ks = 0; ks < 7; ++ks) {
    int kb0 = s * 448 + ks * 64;
    const float* Ap = Kc + (size_t)m * DM + kb0 + kb;
    const float* Bp = Kj + (size_t)m * DM + kb0 + kb;
    #pragma unroll
    for (int q = 0; q < 4; ++q) {
      float4 va = *(const float4*)(Ap + q * 4);
      As[kb + q*4 + 0][m] = va.x;
      As[kb + q*4 + 1][m] = va.y;
      As[kb + q*4 + 2][m] = va.z;
      As[kb + q*4 + 3][m] = va.w;
      float4 vb = *(const float4*)(Bp + q * 4);
      Bs[kb + q*4 + 0][m] = vb.x;
      Bs[kb + q*4 + 1][m] = vb.y;
      Bs[kb + q*4 + 2][m] = vb.z;
      Bs[kb + q*4 + 3][m] = vb.w;
    }
    __syncthreads();
    #pragma unroll 16
    for (int kk = 0; kk < 64; ++kk) {
      float4 a = *(const float4*)&As[kk][ty * 4];
      float4 b = *(const float4*)&Bs[kk][tx * 4];
      MICRO_4x4(As, Bs)
    }
    __syncthreads();
  }
  float* dst = KKsl + ((size_t)p * 7 + s) * 4096;
  #pragma unroll
  for (int r = 0; r < 4; ++r) {
    float4 v = { acc[r][0], acc[r][1], acc[r][2], acc[r][3] };
    *(float4*)&dst[(ty*4 + r) * 64 + tx*4] = v;
  }
}

// KKf[p][4096] = sum of 7 slices
__global__ __launch_bounds__(256) void kkred(
    const float* __restrict__ KKsl, float* __restrict__ KKf) {
  int i = blockIdx.x * 256 + threadIdx.x;   // < 147456
  int pair = i >> 12, e = i & 4095;
  float s = 0.f;
  #pragma unroll
  for (int t = 0; t < 7; ++t) s += KKsl[((size_t)pair * 7 + t) * 4096 + e];
  KKf[i] = s;
}

// ---------------- upfront: Hbase slices = K_all[512,3136] @ W1[3136,512] ----------------
// grid (8 n, 7 ksplit, 8 m)
__global__ __launch_bounds__(256) void hb_slices(
    const float* __restrict__ nkA, const float* __restrict__ W1,
    float* __restrict__ Hb_sl) {
  __shared__ float As[64][64], Bs[64][64];
  int tid = threadIdx.x;
  int n0 = blockIdx.x * 64;
  int sK = blockIdx.y;
  int m0 = blockIdx.z * 64;
  int tx = tid & 15, ty = tid >> 4;
  int m = tid >> 2, kb = (tid & 3) * 16;
  int kr = tid >> 4, nn = (tid & 15) * 4;
  float acc[4][4] = {{0.f}};
  for (int ks = 0; ks < 7; ++ks) {
    int kb0 = sK * 448 + ks * 64;
    const float* Ap = nkA + (size_t)(m0 + m) * DM + kb0 + kb;
    #pragma unroll
    for (int q = 0; q < 4; ++q) {
      float4 v = *(const float4*)(Ap + q * 4);
      As[kb + q*4 + 0][m] = v.x;
      As[kb + q*4 + 1][m] = v.y;
      As[kb + q*4 + 2][m] = v.z;
      As[kb + q*4 + 3][m] = v.w;
      *(float4*)&Bs[kr + q*16][nn] = *(const float4*)(W1 + (size_t)(kb0 + kr + q*16) * DH + n0 + nn);
    }
    __syncthreads();
    #pragma unroll 16
    for (int kk = 0; kk < 64; ++kk) {
      float4 a = *(const float4*)&As[kk][ty * 4];
      float4 b = *(const float4*)&Bs[kk][tx * 4];
      MICRO_4x4(As, Bs)
    }
    __syncthreads();
  }
  #pragma unroll
  for (int r = 0; r < 4; ++r) {
    float4 v = { acc[r][0], acc[r][1], acc[r][2], acc[r][3] };
    *(float4*)&Hb_sl[((size_t)sK * 512 + m0 + ty*4 + r) * 512 + n0 + tx*4] = v;
  }
}

__global__ __launch_bounds__(256) void hbred(
    const float* __restrict__ Hb_sl, float* __restrict__ Hbase) {
  int i = blockIdx.x * 256 + threadIdx.x;   // < 262144
  float s = 0.f;
  #pragma unroll
  for (int t = 0; t < 7; ++t) s += Hb_sl[(size_t)t * 262144 + i];
  Hbase[i] = s;
}

// ---------------- per-chunk: Hcorr[j] = KK[c,j] @ Ew_j   (grid (8 n, c j)) ----------------
__global__ __launch_bounds__(256) void hs_corr(
    const float* __restrict__ KKf, int tri_c,
    const float* __restrict__ Ewstack, float* __restrict__ Hcorr) {
  __shared__ float As[64][64];   // As[i][m] = KK[m][i]
  __shared__ float Bs[64][64];   // Bs[i][n]
  int tid = threadIdx.x;
  int n0 = blockIdx.x * 64;
  int j  = blockIdx.y;
  const float* KK = KKf + (size_t)(tri_c + j) * 4096;
  const float* Ew = Ewstack + (size_t)j * 32768;
  {
    int m = tid >> 2, ib = (tid & 3) * 16;
    #pragma unroll
    for (int q = 0; q < 4; ++q) {
      float4 v = *(const float4*)(KK + m * 64 + ib + q * 4);
      As[ib + q*4 + 0][m] = v.x;
      As[ib + q*4 + 1][m] = v.y;
      As[ib + q*4 + 2][m] = v.z;
      As[ib + q*4 + 3][m] = v.w;
    }
    int kr = tid >> 4, nn = (tid & 15) * 4;
    #pragma unroll
    for (int q = 0; q < 4; ++q)
      *(float4*)&Bs[kr + q*16][nn] = *(const float4*)(Ew + (size_t)(kr + q*16) * DH + n0 + nn);
  }
  __syncthreads();
  int tx = tid & 15, ty = tid >> 4;
  float acc[4][4] = {{0.f}};
  #pragma unroll 16
  for (int kk = 0; kk < 64; ++kk) {
    float4 a = *(const float4*)&As[kk][ty * 4];
    float4 b = *(const float4*)&Bs[kk][tx * 4];
    MICRO_4x4(As, Bs)
  }
  float* dst = Hcorr + (size_t)j * 32768;
  #pragma unroll
  for (int r = 0; r < 4; ++r) {
    float4 v = { acc[r][0], acc[r][1], acc[r][2], acc[r][3] };
    *(float4*)&dst[(ty*4 + r) * DH + n0 + tx*4] = v;
  }
}

// ---------------- per-chunk: H = Hbase_c - sum(corr) ; G,Gp ----------------
__global__ __launch_bounds__(256) void hred_gelu(
    const float* __restrict__ Hb_c, const float* __restrict__ Hcorr, int nsl,
    const float* __restrict__ b1,
    float* __restrict__ H, float* __restrict__ G, float* __restrict__ Gp) {
  int j = blockIdx.x * 256 + threadIdx.x;   // < 32768
  float s = Hb_c[j];
  for (int t = 0; t < nsl; ++t) s -= Hcorr[(size_t)t * 32768 + j];
  H[j] = s;
  float xx = s + b1[j & 511];
  float g, gp;
  gelu_both(xx, g, gp);
  G[j] = g; Gp[j] = gp;
}

// ---------------- per-chunk: Dw + b2 update (grid 49) ----------------
__global__ __launch_bounds__(256) void red_Db2(
    const float* __restrict__ Dp, const float* __restrict__ b2c,
    const float* __restrict__ V, float wc2,
    float* __restrict__ Dw, float* __restrict__ b2n) {
  __shared__ float sm[256];
  int tid = threadIdx.x;
  int col = blockIdx.x * 64 + (tid & 63);
  int r0 = (tid >> 6) * 16;
  float bb = b2c[col];
  float cs = 0.f;
  for (int rr = 0; rr < 16; ++rr) {
    size_t off = (size_t)(r0 + rr) * DM + col;
    float s = 0.f;
    #pragma unroll
    for (int t = 0; t < 8; ++t) s += Dp[(size_t)t * 200704 + off];
    float d = wc2 * (s + bb - V[off]);
    Dw[off] = d;
    cs += d;
  }
  sm[tid] = cs;
  __syncthreads();
  if (tid < 64) {
    float tot = sm[tid] + sm[tid + 64] + sm[tid + 128] + sm[tid + 192];
    b2n[blockIdx.x * 64 + tid] = b2c[blockIdx.x * 64 + tid] - tot;
  }
}

// ---------------- per-chunk: upd64-W2 (0..391) || red_E + b1 update (392..519) ----------------
__global__ __launch_bounds__(256) void comb5(
    const float* __restrict__ G, const float* __restrict__ Dw,
    const float* __restrict__ W2old, float* __restrict__ W2new,
    const float* __restrict__ Esl, const float* __restrict__ Gp,
    float* __restrict__ Ew, const float* __restrict__ b1old, float* __restrict__ b1new) {
  __shared__ float smem[8192];
  int li = blockIdx.x;
  int tid = threadIdx.x;
  if (li < 392) {
    upd64_dev(G, DH, Dw, DM, W2old, W2new, li % 49, li / 49, smem);
  } else {
    int li2 = li - 392;
    int n0 = li2 * 4;
    int row = tid >> 2, c = tid & 3;
    int col = n0 + c;
    float s = 0.f;
    #pragma unroll
    for (int sl = 0; sl < 49; ++sl) s += Esl[(size_t)sl * 32768 + row * 512 + col];
    float ew = s * Gp[row * 512 + col];
    Ew[row * 512 + col] = ew;
    smem[tid] = ew;
    __syncthreads();
    for (int off = 128; off >= 4; off >>= 1) {
      if (tid < off) smem[tid] += smem[tid + off];
      __syncthreads();
    }
    if (tid < 4) b1new[n0 + tid] = b1old[n0 + tid] - smem[tid];
  }
}

// ---------------- per-chunk: G2 = gelu(H - KK[c,c]@Ew_c + b1n)  (grid 32) ----------------
__global__ __launch_bounds__(256) void gelu2k(
    const float* __restrict__ KKcc, const float* __restrict__ Ew,
    const float* __restrict__ H, const float* __restrict__ b1n,
    float* __restrict__ G2) {
  __shared__ float KKs[4096];
  __shared__ float Ews[1024];
  int tid = threadIdx.x;
  int n0 = blockIdx.x * 16;
  #pragma unroll
  for (int q = 0; q < 4; ++q) {
    int e4 = q * 256 + tid;
    *(float4*)&KKs[e4 * 4] = *(const float4*)(KKcc + e4 * 4);
  }
  {
    int i = tid >> 2, c4 = (tid & 3) * 4;
    *(float4*)&Ews[i * 16 + c4] = *(const float4*)(Ew + (size_t)i * DH + n0 + c4);
  }
  __syncthreads();
  #pragma unroll
  for (int q = 0; q < 4; ++q) {
    int e = q * 256 + tid;
    int mrow = e >> 4, cc = e & 15;
    float corr = 0.f;
    #pragma unroll 16
    for (int i = 0; i < 64; ++i) corr += KKs[mrow * 64 + i] * Ews[i * 16 + cc];
    float xx = H[mrow * DH + n0 + cc] - corr + b1n[n0 + cc];
    G2[mrow * DH + n0 + cc] = gelu_only(xx);
  }
}

// ---------------- per-chunk: out = sum(8 slices) + b2n (raw reshape, contiguous) ----------------
__global__ __launch_bounds__(256) void red_Y(
    const float* __restrict__ Dp, const float* __restrict__ b2n,
    float* __restrict__ out, int t0) {
  int j = blockIdx.x * 256 + threadIdx.x;   // < 200704
  float s = 0.f;
  #pragma unroll
  for (int t = 0; t < 8; ++t) s += Dp[(size_t)t * 200704 + j];
  int i = j / DM;
  int d = j - i * DM;
  out[(size_t)t0 * DM + j] = s + b2n[d];
}

extern "C" void kernel_launch(void* const* d_in, const int* in_sizes, int n_in,
                              void* d_out, int out_size, void* d_ws, size_t ws_size,
                              hipStream_t stream) {
  const float* x  = (const float*)d_in[0];
  const float* wk = (const float*)d_in[1];
  const float* bk = (const float*)d_in[2];
  const float* wv = (const float*)d_in[3];
  const float* bv = (const float*)d_in[4];
  const float* sk = (const float*)d_in[5];
  const float* sv = (const float*)d_in[6];
  const float* W1 = (const float*)d_in[7];
  const float* b1 = (const float*)d_in[8];
  const float* W2 = (const float*)d_in[9];
  const float* b2 = (const float*)d_in[10];
  float* out = (float*)d_out;
  float* ws  = (float*)d_ws;

  // workspace layout (floats)
  float* nk      = ws;                  // 1605632
  float* nv      = ws + 1605632;        // 1605632
  float* W2ws    = ws + 3211264;        // 1605632
  float* Spart   = ws + 4816896;        // 1605632
  float* Hb_sl   = ws + 6422528;        // 1835008 (7 x 262144)
  float* Hbase   = ws + 8257536;        // 262144  [512,512]
  float* KKsl    = ws + 8519680;        // 1032192 (36 x 7 x 4096)
  float* KKf     = ws + 9551872;        // 147456  (36 x 4096)
  float* H       = ws + 9699328;        // 32768
  float* G       = ws + 9732096;        // 32768
  float* Gp      = ws + 9764864;        // 32768
  float* Dw      = ws + 9797632;        // 200704
  float* Ewstack = ws + 9998336;        // 262144 (8 x 32768)
  float* Hcorr   = ws + 10260480;       // 229376 (7 x 32768)
  float* b1ws    = ws + 10489856;       // 512
  float* b2ws    = ws + 10490368;       // 3136

  conv_rms<<<1568, 256, 0, stream>>>(x, wk, bk, wv, bv, sk, sv, nk, nv);
  kk_pre<<<dim3(36, 7), 256, 0, stream>>>(nk, KKsl);
  kkred<<<576, 256, 0, stream>>>(KKsl, KKf);
  hb_slices<<<dim3(8, 7, 8), 256, 0, stream>>>(nk, W1, Hb_sl);
  hbred<<<1024, 256, 0, stream>>>(Hb_sl, Hbase);

  // weights[i] = ETA0 * ALPHA^i * (ALPHA^63 / ALPHA^i) = ETA0 * ALPHA^63 (constant)
  float wc2 = 2.0f * (float)(0.1 * pow(0.9, 63.0));

  for (int ch = 0; ch < 8; ++ch) {
    const float* V   = nv + (size_t)ch * 64 * DM;
    const float* W2c = ch ? W2ws : W2;
    const float* b1c = ch ? b1ws : b1;
    const float* b2c = ch ? b2ws : b2;
    int tri_c = ch * (ch + 1) / 2;
    float* Ewc = Ewstack + (size_t)ch * 32768;

    // H(c) = Hbase_c - sum_{j<c} KK[c,j] @ Ew_j ; G, Gp
    if (ch > 0)
      hs_corr<<<dim3(8, ch), 256, 0, stream>>>(KKf, tri_c, Ewstack, Hcorr);
    hred_gelu<<<128, 256, 0, stream>>>(Hbase + (size_t)ch * 32768, Hcorr, ch, b1c, H, G, Gp);
    // P3: pred slices = G @ W2c (split-K 8)
    mm64_nn<<<dim3(49, 8), 256, 0, stream>>>(G, DH, W2c, DM, Spart, DM);
    // Dw = wc2*(pred + b2 - V); b2ws = b2c - colsum(Dw)
    red_Db2<<<49, 256, 0, stream>>>(Spart, b2c, V, wc2, Dw, b2ws);
    // P4: E slices = Dw @ W2c^T (split-K 49)
    mm64_nt<<<dim3(8, 49), 256, 0, stream>>>(Dw, DM, W2c, DM, Spart, DH);
    // P5: W2ws = W2c - G^T Dw  ||  Ew_c = redE*Gp, b1ws = b1c - colsum(Ew)
    comb5<<<520, 256, 0, stream>>>(G, Dw, W2c, W2ws, Spart, Gp, Ewc, b1c, b1ws);
    // recall: G2 = gelu(H - KK[c,c]@Ew_c + b1ws)  (overwrites G)
    gelu2k<<<32, 256, 0, stream>>>(KKf + (size_t)(tri_c + ch) * 4096, Ewc, H, b1ws, G);
    // P7: Y slices = G2 @ W2ws (split-K 8)
    mm64_nn<<<dim3(49, 8), 256, 0, stream>>>(G, DH, W2ws, DM, Spart, DM);
    // out rows = sum + b2ws
    red_Y<<<784, 256, 0, stream>>>(Spart, b2ws, out, ch * 64);
  }
}